// Round 10
// baseline (1107.411 us; speedup 1.0000x reference)
//
#include <hip/hip_runtime.h>
#include <hip/hip_bf16.h>
#include <cstdint>

#define B_SZ   2048
#define D_INN  1024
#define H_SZ   2048
#define D_OUTN 1024
#define TMAX   12

typedef _Float16 f16;
typedef __attribute__((ext_vector_type(8))) _Float16 f16x8;
typedef __attribute__((ext_vector_type(4))) _Float16 f16x4;
typedef __attribute__((ext_vector_type(4))) float    f32x4;

typedef const __attribute__((address_space(1))) uint32_t* gptr_t;
typedef __attribute__((address_space(3))) uint32_t*       lptr_t;
__device__ inline void gld16(const void* g, void* l) {   // 16B global->LDS DMA
    __builtin_amdgcn_global_load_lds((gptr_t)g, (lptr_t)l, 16, 0, 0);
}

// ---------------------------------------------------------------------------
// Split-fp16 NT GEMM, 3-term Markidis (round-7 structure, 75.5us verified):
// 64x128 tile, BK=32, 512 thr / 8 waves of 32x32, 3 LDS buffers + counted
// s_waitcnt vmcnt(3) + raw s_barrier, T2 XOR swizzle both-sides (0 conflicts),
// XCD-chunked bijective blockIdx swizzle. 2 blocks/CU (72KB+1KB LDS).
// NEW: ACT row compaction — A rows gathered through live[] (unique-slot
// permutation: live rows first, halted rows pad the tail), C/dots rows
// scattered through the same map; blocks with m0 >= counts[0] exit early.
// Per-row MFMA math is row-independent -> bitwise identical for live rows.
// Fused epilogue: +Cadd(fp32)+radd; fp32 and/or (hi,lo) fp16 out; per-row
// halt-dot partials from the fp32 accumulator (deterministic fixed order).
// ---------------------------------------------------------------------------
__global__ __launch_bounds__(512, 4) void gemm_split(
    const f16* __restrict__ Ahi, const f16* __restrict__ Alo, int lda,
    const f16* __restrict__ Bhi, const f16* __restrict__ Blo, int ldb,
    const float* __restrict__ Cadd,   // optional [M,ldc] fp32 (orig-row idx)
    const float* __restrict__ radd,   // optional [N] fp32
    float* __restrict__ Cf,           // optional fp32 out
    f16* __restrict__ Chi, f16* __restrict__ Clo,  // optional fp16 pair out
    int ldc, int K, int nx,
    float* __restrict__ dots,         // optional [M][nx] halt-dot partials
    const float* __restrict__ w_halt, // [N] when dots != null
    const int* __restrict__ live,     // optional row permutation (slot->orig)
    const int* __restrict__ counts)   // optional [1] = live count L
{
    __shared__ __align__(16) f16 Ash[3][64 * 32];
    __shared__ __align__(16) f16 Asl[3][64 * 32];
    __shared__ __align__(16) f16 Bsh[3][128 * 32];
    __shared__ __align__(16) f16 Bsl[3][128 * 32];
    __shared__ float dred[4][64];

    const int tid  = threadIdx.x;
    const int wave = tid >> 6;
    const int lane = tid & 63;

    // XCD-chunked bijective blockIdx swizzle (requires nwg % 8 == 0)
    const int nwg = gridDim.x;
    const int cpx = nwg >> 3;
    const int bid = (blockIdx.x & 7) * cpx + (blockIdx.x >> 3);
    const int m0 = (bid / nx) * 64, n0 = (bid % nx) * 128;

    if (counts && m0 >= counts[0]) return;   // tile fully halted (uniform)

    const int wr = wave >> 2, wc = wave & 3;      // 2x4 wave grid, 32x32 tiles
    const int fr = lane & 15, fq = lane >> 4;     // fragment row / k-group

    // --- staging: LDS dest linear 16B chunks; global source chunk swizzled
    //     by the involution c ^= ((c>>3)&3) (== read byte ^ ((row>>1)&3)<<4)
    // A: 256 chunks each; waves 0-3 -> hi, waves 4-7 -> lo; rows via live[]
    const int ac  = tid & 255;
    const int acs = ac ^ ((ac >> 3) & 3);
    const int arow_l = m0 + (acs >> 2);
    const int arow   = live ? live[arow_l] : arow_l;
    const f16* gA = ((wave < 4) ? Ahi : Alo) + (size_t)arow * lda + (acs & 3) * 8;
    f16* dstA0 = (wave < 4) ? &Ash[0][0] : &Asl[0][0];
    const int aofs = (wave & 3) << 9;   // wave-uniform base; HW adds lane*16B
    // B: 512 chunks each of hi/lo (weights, no gather)
    const int bcs = tid ^ ((tid >> 3) & 3);
    const size_t bOff = (size_t)(n0 + (bcs >> 2)) * ldb + (bcs & 3) * 8;
    const f16* gBh = Bhi + bOff;
    const f16* gBl = Blo + bOff;
    const int bofs = wave << 9;

    // swizzled k-invariant fragment read offsets (f16 units)
    int offA[2], offB[2];
#pragma unroll
    for (int m = 0; m < 2; ++m) {
        const int row = wr * 32 + m * 16 + fr;
        offA[m] = row * 32 + ((fq ^ ((row >> 1) & 3)) << 3);
    }
#pragma unroll
    for (int n = 0; n < 2; ++n) {
        const int row = wc * 32 + n * 16 + fr;
        offB[n] = row * 32 + ((fq ^ ((row >> 1) & 3)) << 3);
    }

    f32x4 acc[2][2] = {};

    // prologue: stage tile 0 into buffer 0 (3 loads/thread)
    gld16(gA,  dstA0 + aofs);
    gld16(gBh, &Bsh[0][bofs]);
    gld16(gBl, &Bsl[0][bofs]);

    const int nk = K >> 5;
    int cur = 0;
    for (int ki = 0; ki < nk; ++ki) {
        const int nxt = (cur == 2) ? 0 : cur + 1;
        if (ki + 1 < nk) {
            const int ko = (ki + 1) << 5;
            gld16(gA + ko,  dstA0 + nxt * 2048 + aofs);
            gld16(gBh + ko, &Bsh[nxt][bofs]);
            gld16(gBl + ko, &Bsl[nxt][bofs]);
            // wait for tile ki only; keep tile ki+1's 3 loads in flight
            asm volatile("s_waitcnt vmcnt(3)" ::: "memory");
        } else {
            asm volatile("s_waitcnt vmcnt(0)" ::: "memory");
        }
        __builtin_amdgcn_s_barrier();
        asm volatile("" ::: "memory");   // keep ds_reads below the barrier

        f16x8 ah[2], al[2], bh[2], bl[2];
#pragma unroll
        for (int m = 0; m < 2; ++m) {
            ah[m] = *(const f16x8*)(&Ash[cur][offA[m]]);
            al[m] = *(const f16x8*)(&Asl[cur][offA[m]]);
        }
#pragma unroll
        for (int n = 0; n < 2; ++n) {
            bh[n] = *(const f16x8*)(&Bsh[cur][offB[n]]);
            bl[n] = *(const f16x8*)(&Bsl[cur][offB[n]]);
        }
#pragma unroll
        for (int m = 0; m < 2; ++m)
#pragma unroll
            for (int n = 0; n < 2; ++n)
                acc[m][n] = __builtin_amdgcn_mfma_f32_16x16x32_f16(
                    ah[m], bh[n], acc[m][n], 0, 0, 0);
#pragma unroll
        for (int m = 0; m < 2; ++m)
#pragma unroll
            for (int n = 0; n < 2; ++n)
                acc[m][n] = __builtin_amdgcn_mfma_f32_16x16x32_f16(
                    ah[m], bl[n], acc[m][n], 0, 0, 0);
#pragma unroll
        for (int m = 0; m < 2; ++m)
#pragma unroll
            for (int n = 0; n < 2; ++n)
                acc[m][n] = __builtin_amdgcn_mfma_f32_16x16x32_f16(
                    al[m], bh[n], acc[m][n], 0, 0, 0);
        cur = nxt;
    }

    // epilogue. C/D layout: col = lane&15, row = (lane>>4)*4 + reg
    float whv[2];
    float pd[2][4];
    if (dots) {
#pragma unroll
        for (int n = 0; n < 2; ++n)
            whv[n] = w_halt[n0 + wc * 32 + n * 16 + fr];
#pragma unroll
        for (int m = 0; m < 2; ++m)
#pragma unroll
            for (int r = 0; r < 4; ++r) pd[m][r] = 0.f;
    }

#pragma unroll
    for (int m = 0; m < 2; ++m) {
#pragma unroll
        for (int n = 0; n < 2; ++n) {
#pragma unroll
            for (int r = 0; r < 4; ++r) {
                const int row_l = m0 + wr * 32 + m * 16 + fq * 4 + r;
                const int row = live ? live[row_l] : row_l;
                const int col = n0 + wc * 32 + n * 16 + fr;
                float v = acc[m][n][r];
                if (Cadd) v += Cadd[(size_t)row * ldc + col];
                if (radd) v += radd[col];
                if (Cf) Cf[(size_t)row * ldc + col] = v;
                if (Chi) {
                    const f16 hi = (f16)v;
                    Chi[(size_t)row * ldc + col] = hi;
                    Clo[(size_t)row * ldc + col] = (f16)(v - (float)hi);
                }
                if (dots) pd[m][r] += v * whv[n];
            }
        }
    }

    if (dots) {
        // reduce over the 16-lane fr-group (masks <16 stay within group)
#pragma unroll
        for (int mask = 1; mask < 16; mask <<= 1)
#pragma unroll
            for (int m = 0; m < 2; ++m)
#pragma unroll
                for (int r = 0; r < 4; ++r)
                    pd[m][r] += __shfl_xor(pd[m][r], mask, 64);
        if (fr == 0) {
#pragma unroll
            for (int m = 0; m < 2; ++m)
#pragma unroll
                for (int r = 0; r < 4; ++r)
                    dred[wc][wr * 32 + m * 16 + fq * 4 + r] = pd[m][r];
        }
        __syncthreads();
        if (tid < 64) {
            const float s = dred[0][tid] + dred[1][tid]
                          + dred[2][tid] + dred[3][tid];
            const int row = live ? live[m0 + tid] : (m0 + tid);
            dots[(size_t)row * nx + (bid % nx)] = s;
        }
    }
}

// strided fp32 [rows,cols] (ld) -> contiguous fp16 (hi, lo) pair
__global__ __launch_bounds__(256) void split2d(
    const float* __restrict__ src, int ld, int cols,
    f16* __restrict__ hi, f16* __restrict__ lo, int total4)
{
    const int i = blockIdx.x * 256 + threadIdx.x;
    if (i >= total4) return;
    const int idx = i * 4;
    const int r = idx / cols, c = idx % cols;
    const float4 v = *(const float4*)(src + (size_t)r * ld + c);
    f16x4 h, l;
    h[0] = (f16)v.x; l[0] = (f16)(v.x - (float)h[0]);
    h[1] = (f16)v.y; l[1] = (f16)(v.y - (float)h[1]);
    h[2] = (f16)v.z; l[2] = (f16)(v.z - (float)h[2]);
    h[3] = (f16)v.w; l[3] = (f16)(v.w - (float)h[3]);
    *(f16x4*)(hi + idx) = h;
    *(f16x4*)(lo + idx) = l;
}

// rsum[j] = sum_{k<K} W[j,k]   (the (x+1)-vs-x correction for t==0), fp32
__global__ __launch_bounds__(256) void rowsum_kernel(
    const float* __restrict__ W, int ld, int K, float* __restrict__ out)
{
    const int j = blockIdx.x;
    const int tid = threadIdx.x;
    float s = 0.f;
    for (int k = tid; k < K; k += 256) s += W[(size_t)j * ld + k];
#pragma unroll
    for (int off = 32; off; off >>= 1) s += __shfl_down(s, off);
    __shared__ float red[4];
    if ((tid & 63) == 0) red[tid >> 6] = s;
    __syncthreads();
    if (tid == 0) out[j] = red[0] + red[1] + red[2] + red[3];
}

// Build live[]: live rows ascending at [0,L), halted rows ascending at
// [L,2048) — a PERMUTATION of 0..2047, so gather/scatter never collides.
// Single block, deterministic.
__global__ __launch_bounds__(256) void compact_live(
    const int* __restrict__ halted, int* __restrict__ live,
    int* __restrict__ counts)
{
    __shared__ int part[256];
    const int tid = threadIdx.x;
    int fl[8];
    int lc = 0;
#pragma unroll
    for (int j = 0; j < 8; ++j) {
        fl[j] = (halted[tid * 8 + j] == 0);
        lc += fl[j];
    }
    part[tid] = lc;
    __syncthreads();
    if (tid == 0) {
        int run = 0;
        for (int i = 0; i < 256; ++i) { const int v = part[i]; part[i] = run; run += v; }
        counts[0] = run;
    }
    __syncthreads();
    const int L = counts[0];
    int lpos = part[tid];                    // live cursor (exclusive prefix)
    int hpos = L + (tid * 8 - part[tid]);    // halted cursor
#pragma unroll
    for (int j = 0; j < 8; ++j) {
        const int r = tid * 8 + j;
        if (fl[j]) live[lpos++] = r;
        else       live[hpos++] = r;
    }
}

// Per-step ACT halting + hidden accumulation, one block per batch row.
// Halt dot precomputed in the GEMM epilogue (fp32, deterministic order).
// At t==TMAX-1 also emits the fp16 (hi,lo) split of the final hidden row.
// s_hi may alias hidh — plain pointers, thread-local read-then-write.
__global__ __launch_bounds__(256) void halt_hid(
    const f16* s_hi,                   // [B,H] fp16 hi of s_new
    const float* __restrict__ dots,    // [B][16] partial dots
    const float* __restrict__ b_halt,  // [1]
    float* hidden,                     // [B,H] accumulator (in d_out)
    float* __restrict__ ponder,        // [B]   (in d_out)
    float* __restrict__ cumB,          // [B] state
    float* __restrict__ Rv,            // [B] state
    float* __restrict__ nstep,         // [B] state
    int*   __restrict__ halted,        // [B] state
    f16* hidh, f16* hidl,              // written at t==TMAX-1
    int t)
{
    const int b = blockIdx.x;
    const int tid = threadIdx.x;
    __shared__ float w_sh;
    if (tid == 0) {
        const int hd = (t == 0) ? 0 : halted[b];
        float w;
        if (hd) {
            w = 0.f;
        } else {
            float d = b_halt[0];
#pragma unroll
            for (int i = 0; i < 16; ++i) d += dots[(size_t)b * 16 + i];
            const float p = 1.f / (1.f + expf(-d));
            const float cb = (t == 0) ? 0.f : cumB[b];
            if (cb + p >= 0.99f || t == TMAX - 1) {
                w = 1.f - cb;                 // remainder R
                halted[b] = 1;
                Rv[b] = w;
                nstep[b] = (float)t;
            } else {
                w = p;
                cumB[b] = cb + p;
                if (t == 0) halted[b] = 0;
            }
        }
        w_sh = w;
        if (t == TMAX - 1) ponder[b] = nstep[b] + 1.f + Rv[b];
    }
    __syncthreads();
    const float w = w_sh;
    const bool skip = (t > 0 && w == 0.f);   // halted rows contribute nothing

    float* hrow = hidden + (size_t)b * H_SZ + tid * 8;
    float hv[8];
    if (!skip) {
        const f16x8 vh = *(const f16x8*)(s_hi + (size_t)b * H_SZ + tid * 8);
        if (t == 0) {
#pragma unroll
            for (int j = 0; j < 8; ++j) hv[j] = w * (float)vh[j];
        } else {
            const float4 h0 = *(const float4*)(hrow);
            const float4 h1 = *(const float4*)(hrow + 4);
            hv[0] = h0.x + w * (float)vh[0]; hv[1] = h0.y + w * (float)vh[1];
            hv[2] = h0.z + w * (float)vh[2]; hv[3] = h0.w + w * (float)vh[3];
            hv[4] = h1.x + w * (float)vh[4]; hv[5] = h1.y + w * (float)vh[5];
            hv[6] = h1.z + w * (float)vh[6]; hv[7] = h1.w + w * (float)vh[7];
        }
        *(float4*)(hrow)     = make_float4(hv[0], hv[1], hv[2], hv[3]);
        *(float4*)(hrow + 4) = make_float4(hv[4], hv[5], hv[6], hv[7]);
    }
    if (t == TMAX - 1) {
        if (skip) {
            const float4 h0 = *(const float4*)(hrow);
            const float4 h1 = *(const float4*)(hrow + 4);
            hv[0] = h0.x; hv[1] = h0.y; hv[2] = h0.z; hv[3] = h0.w;
            hv[4] = h1.x; hv[5] = h1.y; hv[6] = h1.z; hv[7] = h1.w;
        }
        f16x8 hh, hl;
#pragma unroll
        for (int j = 0; j < 8; ++j) {
            const f16 hi = (f16)hv[j];
            hh[j] = hi;
            hl[j] = (f16)(hv[j] - (float)hi);
        }
        *(f16x8*)(hidh + (size_t)b * H_SZ + tid * 8) = hh;
        *(f16x8*)(hidl + (size_t)b * H_SZ + tid * 8) = hl;
    }
}

extern "C" void kernel_launch(void* const* d_in, const int* in_sizes, int n_in,
                              void* d_out, int out_size, void* d_ws, size_t ws_size,
                              hipStream_t stream)
{
    const float* x        = (const float*)d_in[0];   // [B, D_IN]
    const float* h        = (const float*)d_in[1];   // [B, H]
    const float* W_hidden = (const float*)d_in[2];   // [H, D_IN+H]
    const float* b_hidden = (const float*)d_in[3];   // [H]
    const float* w_halt   = (const float*)d_in[4];   // [H]
    const float* b_halt   = (const float*)d_in[5];   // [1]
    const float* W_out    = (const float*)d_in[6];   // [D_OUT, H]
    const float* b_out    = (const float*)d_in[7];   // [D_OUT]

    float* out    = (float*)d_out;
    float* output = out;                                   // [B, D_OUT]
    float* hidden = out + (size_t)B_SZ * D_OUTN;           // [B, H]
    float* ponder = hidden + (size_t)B_SZ * H_SZ;          // [B]

    // ---- workspace layout ----
    float* ws     = (float*)d_ws;
    float* xc     = ws;                                    // [B,H] fp32 16MB
    float* rsum   = xc + (size_t)B_SZ * H_SZ;              // [H]
    float* cumB   = rsum + H_SZ;                           // [B]
    float* Rv     = cumB + B_SZ;                           // [B]
    float* nstep  = Rv + B_SZ;                             // [B]
    int*   halted = (int*)(nstep + B_SZ);                  // [B]
    int*   live   = halted + B_SZ;                         // [B]
    int*   counts = live + B_SZ;                           // [1] (+pad)
    float* dots   = (float*)(counts + 64);                 // [B][16] 128KB
    f16*   fh     = (f16*)(dots + (size_t)B_SZ * 16);
    f16* xh  = fh;                         // [B,D_IN]  4MB
    f16* xl  = xh  + (size_t)B_SZ * D_INN;
    f16* sh0 = xl  + (size_t)B_SZ * D_INN; // [B,H] 8MB
    f16* sl0 = sh0 + (size_t)B_SZ * H_SZ;
    f16* sh1 = sl0 + (size_t)B_SZ * H_SZ;
    f16* sl1 = sh1 + (size_t)B_SZ * H_SZ;
    f16* Wxh = sl1 + (size_t)B_SZ * H_SZ;  // [H,D_IN] 4MB
    f16* Wxl = Wxh + (size_t)H_SZ * D_INN;
    f16* Wsh = Wxl + (size_t)H_SZ * D_INN; // [H,H] 8MB
    f16* Wsl = Wsh + (size_t)H_SZ * H_SZ;
    f16* Woh = Wsl + (size_t)H_SZ * H_SZ;  // [D_OUT,H] 4MB
    f16* Wol = Woh + (size_t)D_OUTN * H_SZ;
    f16* hidh = sh0;                       // reuse after the t-loop (aliases
    f16* hidl = sl0;                       // t=11's s_new; safe: see halt_hid)

    const dim3 blk(256);
    const dim3 gblk(512);
    const int LDW = D_INN + H_SZ;  // 3072

    // one-time fp32 -> fp16 (hi,lo) splits
    split2d<<<dim3(B_SZ * D_INN / 4 / 256), blk, 0, stream>>>(
        x, D_INN, D_INN, xh, xl, B_SZ * D_INN / 4);
    split2d<<<dim3(B_SZ * H_SZ / 4 / 256), blk, 0, stream>>>(
        h, H_SZ, H_SZ, sh0, sl0, B_SZ * H_SZ / 4);
    split2d<<<dim3(H_SZ * D_INN / 4 / 256), blk, 0, stream>>>(
        W_hidden, LDW, D_INN, Wxh, Wxl, H_SZ * D_INN / 4);
    split2d<<<dim3(H_SZ * H_SZ / 4 / 256), blk, 0, stream>>>(
        W_hidden + D_INN, LDW, H_SZ, Wsh, Wsl, H_SZ * H_SZ / 4);
    split2d<<<dim3(D_OUTN * H_SZ / 4 / 256), blk, 0, stream>>>(
        W_out, H_SZ, H_SZ, Woh, Wol, D_OUTN * H_SZ / 4);

    // rsum[j] = sum_k W_x[j,k]   (xin = x+1 correction at t==0)
    rowsum_kernel<<<dim3(H_SZ), blk, 0, stream>>>(W_hidden, LDW, D_INN, rsum);

    // grids (1-D, XCD-swizzled in-kernel; all % 8 == 0)
    const int g_step = (B_SZ / 64) * (H_SZ / 128);    // 32*16 = 512
    const int g_out  = (B_SZ / 64) * (D_OUTN / 128);  // 32*8  = 256

    // xc = x @ W_x^T + b_hidden   (loop-invariant part, fp32)
    gemm_split<<<dim3(g_step), gblk, 0, stream>>>(
        xh, xl, D_INN, Wxh, Wxl, D_INN, nullptr, b_hidden,
        xc, nullptr, nullptr, H_SZ, D_INN, H_SZ / 128,
        nullptr, nullptr, nullptr, nullptr);

    for (int t = 0; t < TMAX; ++t) {
        const f16* ph = (t & 1) ? sh1 : sh0;
        const f16* pl = (t & 1) ? sl1 : sl0;
        f16*       nh = (t & 1) ? sh0 : sh1;
        f16*       nl = (t & 1) ? sl0 : sl1;
        const int* lv = (t == 0) ? nullptr : live;
        const int* ct = (t == 0) ? nullptr : counts;
        // s_new = s_prev @ W_s^T + xc (+ rsum at t==0); fused halt-dot
        // partials; live-row gather/scatter + early-exit for halted tiles
        gemm_split<<<dim3(g_step), gblk, 0, stream>>>(
            ph, pl, H_SZ, Wsh, Wsl, H_SZ, xc, (t == 0) ? rsum : nullptr,
            nullptr, nh, nl, H_SZ, H_SZ, H_SZ / 128, dots, w_halt, lv, ct);
        halt_hid<<<dim3(B_SZ), blk, 0, stream>>>(
            nh, dots, b_halt, hidden, ponder, cumB, Rv, nstep, halted,
            hidh, hidl, t);
        if (t < TMAX - 1)
            compact_live<<<dim3(1), blk, 0, stream>>>(halted, live, counts);
    }

    // output = hidden @ W_out^T + b_out   (Σw = 1 ⇒ projection commutes)
    gemm_split<<<dim3(g_out), gblk, 0, stream>>>(
        hidh, hidl, H_SZ, Woh, Wol, H_SZ, nullptr, b_out,
        output, nullptr, nullptr, D_OUTN, H_SZ, D_OUTN / 128,
        nullptr, nullptr, nullptr, nullptr);
}

// Round 11
// 1019.319 us; speedup vs baseline: 1.0864x; 1.0864x over previous
//
#include <hip/hip_runtime.h>
#include <hip/hip_bf16.h>
#include <cstdint>

#define B_SZ   2048
#define D_INN  1024
#define H_SZ   2048
#define D_OUTN 1024
#define TMAX   12

typedef _Float16 f16;
typedef __attribute__((ext_vector_type(8))) _Float16 f16x8;
typedef __attribute__((ext_vector_type(4))) _Float16 f16x4;
typedef __attribute__((ext_vector_type(4))) float    f32x4;

typedef const __attribute__((address_space(1))) uint32_t* gptr_t;
typedef __attribute__((address_space(3))) uint32_t*       lptr_t;
__device__ inline void gld16(const void* g, void* l) {   // 16B global->LDS DMA
    __builtin_amdgcn_global_load_lds((gptr_t)g, (lptr_t)l, 16, 0, 0);
}

// ---------------------------------------------------------------------------
// Split-fp16 NT GEMM, 3-term Markidis: C ≈ Ahi·Bhi + Ahi·Blo + Alo·Bhi.
// Round-7 verified structure (75.5us): 64x128 tile, BK=32, 512 thr / 8 waves
// of 32x32, 3 LDS buffers, counted s_waitcnt vmcnt(3) + raw s_barrier,
// T2 XOR swizzle both-sides (0 conflicts), XCD-chunked bijective blockIdx
// swizzle, 2 blocks/CU (72KB LDS).
// NEW (this round): prefetch DISTANCE 2 at the same 3 buffers. Legal because
// STAGE((ki+2)%3) is issued AFTER the top-of-iteration barrier: at that
// point every wave has finished its reads of buf[(ki-1)%3] (= the write
// target), so no 4th buffer is needed. Issue-to-wait distance becomes two
// iterations -> 2x HBM-latency tolerance; vmcnt numbers unchanged.
// Epilogue: +Cadd (fp32), +radd; writes Cf (fp32) and/or (Chi,Clo) pair.
// ---------------------------------------------------------------------------
__global__ __launch_bounds__(512, 4) void gemm_split(
    const f16* __restrict__ Ahi, const f16* __restrict__ Alo, int lda,
    const f16* __restrict__ Bhi, const f16* __restrict__ Blo, int ldb,
    const float* __restrict__ Cadd,   // optional [M,ldc] fp32
    const float* __restrict__ radd,   // optional [N] fp32
    float* __restrict__ Cf,           // optional fp32 out
    f16* __restrict__ Chi, f16* __restrict__ Clo,  // optional fp16 pair out
    int ldc, int K, int nx)
{
    __shared__ __align__(16) f16 Ash[3][64 * 32];
    __shared__ __align__(16) f16 Asl[3][64 * 32];
    __shared__ __align__(16) f16 Bsh[3][128 * 32];
    __shared__ __align__(16) f16 Bsl[3][128 * 32];
    const int tid  = threadIdx.x;
    const int wave = tid >> 6;
    const int lane = tid & 63;

    // XCD-chunked bijective blockIdx swizzle (requires nwg % 8 == 0)
    const int nwg = gridDim.x;
    const int cpx = nwg >> 3;
    const int bid = (blockIdx.x & 7) * cpx + (blockIdx.x >> 3);
    const int m0 = (bid / nx) * 64, n0 = (bid % nx) * 128;

    const int wr = wave >> 2, wc = wave & 3;      // 2x4 wave grid, 32x32 tiles
    const int fr = lane & 15, fq = lane >> 4;     // fragment row / k-group

    // --- staging: LDS dest linear 16B chunks; global source chunk swizzled
    //     by the involution c ^= ((c>>3)&3) (== read byte ^ ((row>>1)&3)<<4)
    // A: 256 chunks each; waves 0-3 -> hi, waves 4-7 -> lo
    const int ac  = tid & 255;
    const int acs = ac ^ ((ac >> 3) & 3);
    const f16* gA = ((wave < 4) ? Ahi : Alo)
                  + (size_t)(m0 + (acs >> 2)) * lda + (acs & 3) * 8;
    f16* dstA0 = (wave < 4) ? &Ash[0][0] : &Asl[0][0];
    const int aofs = (wave & 3) << 9;   // wave-uniform base; HW adds lane*16B
    // B: 512 chunks each of hi/lo (weights)
    const int bcs = tid ^ ((tid >> 3) & 3);
    const size_t bOff = (size_t)(n0 + (bcs >> 2)) * ldb + (bcs & 3) * 8;
    const f16* gBh = Bhi + bOff;
    const f16* gBl = Blo + bOff;
    const int bofs = wave << 9;

    // swizzled k-invariant fragment read offsets (f16 units)
    int offA[2], offB[2];
#pragma unroll
    for (int m = 0; m < 2; ++m) {
        const int row = wr * 32 + m * 16 + fr;
        offA[m] = row * 32 + ((fq ^ ((row >> 1) & 3)) << 3);
    }
#pragma unroll
    for (int n = 0; n < 2; ++n) {
        const int row = wc * 32 + n * 16 + fr;
        offB[n] = row * 32 + ((fq ^ ((row >> 1) & 3)) << 3);
    }

    auto STAGE = [&](int buf, int ko) {
        gld16(gA + ko,  dstA0 + buf * 2048 + aofs);
        gld16(gBh + ko, &Bsh[buf][bofs]);
        gld16(gBl + ko, &Bsl[buf][bofs]);
    };

    f32x4 acc[2][2] = {};

    const int nk = K >> 5;
    // prologue: stage tiles 0 and 1 (prefetch distance 2)
    STAGE(0, 0);
    STAGE(1, 32);            // K >= 64 always here

    int cur = 0;
    for (int ki = 0; ki < nk; ++ki) {
        // wait for tile ki's 3 loads (the newest 3 — tile ki+1's — may fly)
        if (ki + 1 < nk) {
            asm volatile("s_waitcnt vmcnt(3)" ::: "memory");
        } else {
            asm volatile("s_waitcnt vmcnt(0)" ::: "memory");
        }
        __builtin_amdgcn_s_barrier();
        asm volatile("" ::: "memory");   // keep everything below the barrier

        // stage tile ki+2 into buf (ki+2)%3 == (cur-1)%3 — safe: after the
        // barrier, all waves have finished reading that buffer (iter ki-1).
        if (ki + 2 < nk) {
            const int b2 = (cur == 0) ? 2 : cur - 1;
            STAGE(b2, (ki + 2) << 5);
        }

        f16x8 ah[2], al[2], bh[2], bl[2];
#pragma unroll
        for (int m = 0; m < 2; ++m) {
            ah[m] = *(const f16x8*)(&Ash[cur][offA[m]]);
            al[m] = *(const f16x8*)(&Asl[cur][offA[m]]);
        }
#pragma unroll
        for (int n = 0; n < 2; ++n) {
            bh[n] = *(const f16x8*)(&Bsh[cur][offB[n]]);
            bl[n] = *(const f16x8*)(&Bsl[cur][offB[n]]);
        }
#pragma unroll
        for (int m = 0; m < 2; ++m)
#pragma unroll
            for (int n = 0; n < 2; ++n)
                acc[m][n] = __builtin_amdgcn_mfma_f32_16x16x32_f16(
                    ah[m], bh[n], acc[m][n], 0, 0, 0);
#pragma unroll
        for (int m = 0; m < 2; ++m)
#pragma unroll
            for (int n = 0; n < 2; ++n)
                acc[m][n] = __builtin_amdgcn_mfma_f32_16x16x32_f16(
                    ah[m], bl[n], acc[m][n], 0, 0, 0);
#pragma unroll
        for (int m = 0; m < 2; ++m)
#pragma unroll
            for (int n = 0; n < 2; ++n)
                acc[m][n] = __builtin_amdgcn_mfma_f32_16x16x32_f16(
                    al[m], bh[n], acc[m][n], 0, 0, 0);
        cur = (cur == 2) ? 0 : cur + 1;
    }

    // C/D layout: col = lane&15, row = (lane>>4)*4 + reg   [m89/m91 verified]
#pragma unroll
    for (int m = 0; m < 2; ++m) {
#pragma unroll
        for (int n = 0; n < 2; ++n) {
#pragma unroll
            for (int r = 0; r < 4; ++r) {
                const int row = m0 + wr * 32 + m * 16 + fq * 4 + r;
                const int col = n0 + wc * 32 + n * 16 + fr;
                float v = acc[m][n][r];
                if (Cadd) v += Cadd[(size_t)row * ldc + col];
                if (radd) v += radd[col];
                if (Cf) Cf[(size_t)row * ldc + col] = v;
                if (Chi) {
                    const f16 hi = (f16)v;
                    Chi[(size_t)row * ldc + col] = hi;
                    Clo[(size_t)row * ldc + col] = (f16)(v - (float)hi);
                }
            }
        }
    }
}

// strided fp32 [rows,cols] (ld) -> contiguous fp16 (hi, lo) pair
__global__ __launch_bounds__(256) void split2d(
    const float* __restrict__ src, int ld, int cols,
    f16* __restrict__ hi, f16* __restrict__ lo, int total4)
{
    const int i = blockIdx.x * 256 + threadIdx.x;
    if (i >= total4) return;
    const int idx = i * 4;
    const int r = idx / cols, c = idx % cols;
    const float4 v = *(const float4*)(src + (size_t)r * ld + c);
    f16x4 h, l;
    h[0] = (f16)v.x; l[0] = (f16)(v.x - (float)h[0]);
    h[1] = (f16)v.y; l[1] = (f16)(v.y - (float)h[1]);
    h[2] = (f16)v.z; l[2] = (f16)(v.z - (float)h[2]);
    h[3] = (f16)v.w; l[3] = (f16)(v.w - (float)h[3]);
    *(f16x4*)(hi + idx) = h;
    *(f16x4*)(lo + idx) = l;
}

// rsum[j] = sum_{k<K} W[j,k]   (the (x+1)-vs-x correction for t==0), fp32
__global__ __launch_bounds__(256) void rowsum_kernel(
    const float* __restrict__ W, int ld, int K, float* __restrict__ out)
{
    const int j = blockIdx.x;
    const int tid = threadIdx.x;
    float s = 0.f;
    for (int k = tid; k < K; k += 256) s += W[(size_t)j * ld + k];
#pragma unroll
    for (int off = 32; off; off >>= 1) s += __shfl_down(s, off);
    __shared__ float red[4];
    if ((tid & 63) == 0) red[tid >> 6] = s;
    __syncthreads();
    if (tid == 0) out[j] = red[0] + red[1] + red[2] + red[3];
}

// Per-step ACT halting + weighted accumulation of hidden. 1 block / row.
// s reconstructed as hi+lo (error ~2^-22 rel) so halting decisions match fp32.
// At t==TMAX-1 also emits the fp16 (hi,lo) split of the final hidden row
// (replaces a separate split2d). s_hi/s_lo may alias hidh/hidl — plain
// pointers, thread-local read-then-write at identical offsets.
__global__ __launch_bounds__(256) void halt_accum(
    const f16* s_hi, const f16* s_lo,  // [B,H]
    const float* __restrict__ w_halt,  // [H]
    const float* __restrict__ b_halt,  // [1]
    float* hidden,                     // [B,H] accumulator (in d_out)
    float* __restrict__ ponder,        // [B]   (in d_out)
    float* __restrict__ cumB,          // [B] state
    float* __restrict__ Rv,            // [B] state
    float* __restrict__ nstep,         // [B] state
    int*   __restrict__ halted,        // [B] state
    f16* hidh, f16* hidl,              // written at t==TMAX-1
    int t)
{
    const int b = blockIdx.x;
    const int tid = threadIdx.x;
    const f16x8 vh = *(const f16x8*)(s_hi + (size_t)b * H_SZ + tid * 8);
    const f16x8 vl = *(const f16x8*)(s_lo + (size_t)b * H_SZ + tid * 8);
    float s[8];
#pragma unroll
    for (int j = 0; j < 8; ++j) s[j] = (float)vh[j] + (float)vl[j];
    const float4 w0 = *(const float4*)(w_halt + tid * 8);
    const float4 w1 = *(const float4*)(w_halt + tid * 8 + 4);
    float part = s[0] * w0.x + s[1] * w0.y + s[2] * w0.z + s[3] * w0.w
               + s[4] * w1.x + s[5] * w1.y + s[6] * w1.z + s[7] * w1.w;
#pragma unroll
    for (int off = 32; off; off >>= 1) part += __shfl_down(part, off);

    __shared__ float red[4];
    __shared__ float w_sh;
    if ((tid & 63) == 0) red[tid >> 6] = part;
    __syncthreads();
    if (tid == 0) {
        const float dot = red[0] + red[1] + red[2] + red[3] + b_halt[0];
        const float p = 1.f / (1.f + expf(-dot));
        const float cb = (t == 0) ? 0.f : cumB[b];
        const int   hd = (t == 0) ? 0   : halted[b];
        float w;
        if (hd) {
            w = 0.f;
        } else if (cb + p >= 0.99f || t == TMAX - 1) {
            w = 1.f - cb;                 // remainder R
            halted[b] = 1;
            Rv[b] = w;
            nstep[b] = (float)t;
        } else {
            w = p;
            cumB[b] = cb + p;
            if (t == 0) halted[b] = 0;
        }
        w_sh = w;
        if (t == TMAX - 1) ponder[b] = nstep[b] + 1.f + Rv[b];
    }
    __syncthreads();
    const float w = w_sh;
    const bool skip = (t > 0 && w == 0.f);   // halted rows contribute nothing

    float* hrow = hidden + (size_t)b * H_SZ + tid * 8;
    float hv[8];
    if (!skip) {
        if (t == 0) {
#pragma unroll
            for (int j = 0; j < 8; ++j) hv[j] = w * s[j];
        } else {
            const float4 h0 = *(const float4*)(hrow);
            const float4 h1 = *(const float4*)(hrow + 4);
            hv[0] = h0.x + w * s[0]; hv[1] = h0.y + w * s[1];
            hv[2] = h0.z + w * s[2]; hv[3] = h0.w + w * s[3];
            hv[4] = h1.x + w * s[4]; hv[5] = h1.y + w * s[5];
            hv[6] = h1.z + w * s[6]; hv[7] = h1.w + w * s[7];
        }
        *(float4*)(hrow)     = make_float4(hv[0], hv[1], hv[2], hv[3]);
        *(float4*)(hrow + 4) = make_float4(hv[4], hv[5], hv[6], hv[7]);
    }
    if (t == TMAX - 1) {
        if (skip) {
            const float4 h0 = *(const float4*)(hrow);
            const float4 h1 = *(const float4*)(hrow + 4);
            hv[0] = h0.x; hv[1] = h0.y; hv[2] = h0.z; hv[3] = h0.w;
            hv[4] = h1.x; hv[5] = h1.y; hv[6] = h1.z; hv[7] = h1.w;
        }
        f16x8 hh, hl;
#pragma unroll
        for (int j = 0; j < 8; ++j) {
            const f16 hi = (f16)hv[j];
            hh[j] = hi;
            hl[j] = (f16)(hv[j] - (float)hi);
        }
        *(f16x8*)(hidh + (size_t)b * H_SZ + tid * 8) = hh;
        *(f16x8*)(hidl + (size_t)b * H_SZ + tid * 8) = hl;
    }
}

extern "C" void kernel_launch(void* const* d_in, const int* in_sizes, int n_in,
                              void* d_out, int out_size, void* d_ws, size_t ws_size,
                              hipStream_t stream)
{
    const float* x        = (const float*)d_in[0];   // [B, D_IN]
    const float* h        = (const float*)d_in[1];   // [B, H]
    const float* W_hidden = (const float*)d_in[2];   // [H, D_IN+H]
    const float* b_hidden = (const float*)d_in[3];   // [H]
    const float* w_halt   = (const float*)d_in[4];   // [H]
    const float* b_halt   = (const float*)d_in[5];   // [1]
    const float* W_out    = (const float*)d_in[6];   // [D_OUT, H]
    const float* b_out    = (const float*)d_in[7];   // [D_OUT]

    float* out    = (float*)d_out;
    float* output = out;                                   // [B, D_OUT]
    float* hidden = out + (size_t)B_SZ * D_OUTN;           // [B, H]
    float* ponder = hidden + (size_t)B_SZ * H_SZ;          // [B]

    // ---- workspace layout ----
    float* ws     = (float*)d_ws;
    float* xc     = ws;                                    // [B,H] fp32 16MB
    float* rsum   = xc + (size_t)B_SZ * H_SZ;              // [H]
    float* cumB   = rsum + H_SZ;                           // [B]
    float* Rv     = cumB + B_SZ;                           // [B]
    float* nstep  = Rv + B_SZ;                             // [B]
    int*   halted = (int*)(nstep + B_SZ);                  // [B]
    f16*   fh     = (f16*)(halted + B_SZ);
    f16* xh  = fh;                         // [B,D_IN]  4MB
    f16* xl  = xh  + (size_t)B_SZ * D_INN;
    f16* sh0 = xl  + (size_t)B_SZ * D_INN; // [B,H] 8MB
    f16* sl0 = sh0 + (size_t)B_SZ * H_SZ;
    f16* sh1 = sl0 + (size_t)B_SZ * H_SZ;
    f16* sl1 = sh1 + (size_t)B_SZ * H_SZ;
    f16* Wxh = sl1 + (size_t)B_SZ * H_SZ;  // [H,D_IN] 4MB
    f16* Wxl = Wxh + (size_t)H_SZ * D_INN;
    f16* Wsh = Wxl + (size_t)H_SZ * D_INN; // [H,H] 8MB
    f16* Wsl = Wsh + (size_t)H_SZ * H_SZ;
    f16* Woh = Wsl + (size_t)H_SZ * H_SZ;  // [D_OUT,H] 4MB
    f16* Wol = Woh + (size_t)D_OUTN * H_SZ;
    f16* hidh = sh0;                       // reuse after the t-loop (aliases
    f16* hidl = sl0;                       // t=11's s_new; safe: see halt_accum)

    const dim3 blk(256);
    const dim3 gblk(512);
    const int LDW = D_INN + H_SZ;  // 3072

    // one-time fp32 -> fp16 (hi,lo) splits
    split2d<<<dim3(B_SZ * D_INN / 4 / 256), blk, 0, stream>>>(
        x, D_INN, D_INN, xh, xl, B_SZ * D_INN / 4);
    split2d<<<dim3(B_SZ * H_SZ / 4 / 256), blk, 0, stream>>>(
        h, H_SZ, H_SZ, sh0, sl0, B_SZ * H_SZ / 4);
    split2d<<<dim3(H_SZ * D_INN / 4 / 256), blk, 0, stream>>>(
        W_hidden, LDW, D_INN, Wxh, Wxl, H_SZ * D_INN / 4);
    split2d<<<dim3(H_SZ * H_SZ / 4 / 256), blk, 0, stream>>>(
        W_hidden + D_INN, LDW, H_SZ, Wsh, Wsl, H_SZ * H_SZ / 4);
    split2d<<<dim3(D_OUTN * H_SZ / 4 / 256), blk, 0, stream>>>(
        W_out, H_SZ, H_SZ, Woh, Wol, D_OUTN * H_SZ / 4);

    // rsum[j] = sum_k W_x[j,k]   (xin = x+1 correction at t==0)
    rowsum_kernel<<<dim3(H_SZ), blk, 0, stream>>>(W_hidden, LDW, D_INN, rsum);

    // grids (1-D, XCD-swizzled in-kernel; all % 8 == 0)
    const int g_step = (B_SZ / 64) * (H_SZ / 128);    // 32*16 = 512
    const int g_out  = (B_SZ / 64) * (D_OUTN / 128);  // 32*8  = 256

    // xc = x @ W_x^T + b_hidden   (loop-invariant part, fp32)
    gemm_split<<<dim3(g_step), gblk, 0, stream>>>(
        xh, xl, D_INN, Wxh, Wxl, D_INN, nullptr, b_hidden,
        xc, nullptr, nullptr, H_SZ, D_INN, H_SZ / 128);

    for (int t = 0; t < TMAX; ++t) {
        const f16* ph = (t & 1) ? sh1 : sh0;
        const f16* pl = (t & 1) ? sl1 : sl0;
        f16*       nh = (t & 1) ? sh0 : sh1;
        f16*       nl = (t & 1) ? sl0 : sl1;
        // s_new = s_prev @ W_s^T + xc (+ rsum at t==0), written as (hi,lo)
        gemm_split<<<dim3(g_step), gblk, 0, stream>>>(
            ph, pl, H_SZ, Wsh, Wsl, H_SZ, xc, (t == 0) ? rsum : nullptr,
            nullptr, nh, nl, H_SZ, H_SZ, H_SZ / 128);
        halt_accum<<<dim3(B_SZ), blk, 0, stream>>>(
            nh, nl, w_halt, b_halt, hidden, ponder, cumB, Rv, nstep, halted,
            hidh, hidl, t);
    }

    // output = hidden @ W_out^T + b_out   (Σw = 1 ⇒ projection commutes)
    gemm_split<<<dim3(g_out), gblk, 0, stream>>>(
        hidh, hidl, H_SZ, Woh, Wol, H_SZ, nullptr, b_out,
        output, nullptr, nullptr, D_OUTN, H_SZ, D_OUTN / 128);
}

// Round 12
// 976.967 us; speedup vs baseline: 1.1335x; 1.0434x over previous
//
#include <hip/hip_runtime.h>
#include <hip/hip_bf16.h>
#include <cstdint>

#define B_SZ   2048
#define D_INN  1024
#define H_SZ   2048
#define D_OUTN 1024
#define TMAX   12

typedef _Float16 f16;
typedef __attribute__((ext_vector_type(8))) _Float16 f16x8;
typedef __attribute__((ext_vector_type(4))) _Float16 f16x4;
typedef __attribute__((ext_vector_type(4))) float    f32x4;

typedef const __attribute__((address_space(1))) uint32_t* gptr_t;
typedef __attribute__((address_space(3))) uint32_t*       lptr_t;
__device__ inline void gld16(const void* g, void* l) {   // 16B global->LDS DMA
    __builtin_amdgcn_global_load_lds((gptr_t)g, (lptr_t)l, 16, 0, 0);
}

// ---------------------------------------------------------------------------
// Split-fp16 NT GEMM, 3-term Markidis: C ≈ Ahi·Bhi + Ahi·Blo + Alo·Bhi.
// ROUND-7 VERIFIED SCHEDULE (75.5us @ BN=128), templated on BN:
//   64xBN tile, BK=32, 512 thr / 8 waves (2x4 wave grid, 32x(BN/4) tiles),
//   3 LDS buffers, in-loop: STAGE(ki+1) -> s_waitcnt vmcnt(NV) -> s_barrier
//   -> ds_read -> 3 MFMA passes. NV = loads/thread/STAGE (3 for BN=128,
//   2 for BN=64). T2 XOR swizzle both-sides (0 conflicts measured),
//   XCD-chunked bijective blockIdx swizzle. 2 blocks/CU both variants
//   (LDS 72KB / 48KB).
// BN=64 exists so the out-projection GEMM (N=1024) gets grid 512 = 2
// blocks/CU instead of 256 = 1 (the round-5/6 occupancy lesson).
// Epilogue: +Cadd (fp32), +radd; writes Cf (fp32) and/or (Chi,Clo) pair.
// ---------------------------------------------------------------------------
template<int BN>
__global__ __launch_bounds__(512, 4) void gemm_split(
    const f16* __restrict__ Ahi, const f16* __restrict__ Alo, int lda,
    const f16* __restrict__ Bhi, const f16* __restrict__ Blo, int ldb,
    const float* __restrict__ Cadd,   // optional [M,ldc] fp32
    const float* __restrict__ radd,   // optional [N] fp32
    float* __restrict__ Cf,           // optional fp32 out
    f16* __restrict__ Chi, f16* __restrict__ Clo,  // optional fp16 pair out
    int ldc, int K, int nx)
{
    constexpr int WN = BN / 64;             // n-frags per wave (2 or 1)
    constexpr int NV = (BN == 128) ? 3 : 2; // vmem loads/thread/STAGE
    __shared__ __align__(16) f16 Ash[3][64 * 32];
    __shared__ __align__(16) f16 Asl[3][64 * 32];
    __shared__ __align__(16) f16 Bsh[3][BN * 32];
    __shared__ __align__(16) f16 Bsl[3][BN * 32];
    const int tid  = threadIdx.x;
    const int wave = tid >> 6;
    const int lane = tid & 63;

    // XCD-chunked bijective blockIdx swizzle (requires nwg % 8 == 0)
    const int nwg = gridDim.x;
    const int cpx = nwg >> 3;
    const int bid = (blockIdx.x & 7) * cpx + (blockIdx.x >> 3);
    const int m0 = (bid / nx) * 64, n0 = (bid % nx) * BN;

    const int wr = wave >> 2, wc = wave & 3;      // 2x4 wave grid
    const int fr = lane & 15, fq = lane >> 4;     // fragment row / k-group

    // --- staging: LDS dest linear 16B chunks; global source chunk swizzled
    //     by the involution c ^= ((c>>3)&3) (== read byte ^ ((row>>1)&3)<<4)
    // A: 256 chunks each; waves 0-3 -> hi, waves 4-7 -> lo
    const int ac  = tid & 255;
    const int acs = ac ^ ((ac >> 3) & 3);
    const f16* gA = ((wave < 4) ? Ahi : Alo)
                  + (size_t)(m0 + (acs >> 2)) * lda + (acs & 3) * 8;
    f16* dstA0 = (wave < 4) ? &Ash[0][0] : &Asl[0][0];
    const int aofs = (wave & 3) << 9;   // wave-uniform base; HW adds lane*16B

    // B staging (variant-dependent)
    const f16* gBh = nullptr; const f16* gBl = nullptr;  // BN==128 path
    const f16* gB  = nullptr; f16* dstB0 = nullptr;      // BN==64 path
    int bofs;
    if constexpr (BN == 128) {           // 512 chunks each: 1 Bh + 1 Bl/thread
        const int bcs = tid ^ ((tid >> 3) & 3);
        const size_t bOff = (size_t)(n0 + (bcs >> 2)) * ldb + (bcs & 3) * 8;
        gBh = Bhi + bOff;
        gBl = Blo + bOff;
        bofs = wave << 9;
    } else {                             // 256 chunks: waves 0-3 hi, 4-7 lo
        const int bc  = tid & 255;
        const int bcs = bc ^ ((bc >> 3) & 3);
        gB = ((wave < 4) ? Bhi : Blo)
           + (size_t)(n0 + (bcs >> 2)) * ldb + (bcs & 3) * 8;
        dstB0 = (wave < 4) ? &Bsh[0][0] : &Bsl[0][0];
        bofs = (wave & 3) << 9;
    }

    // swizzled k-invariant fragment read offsets (f16 units)
    int offA[2], offB[WN];
#pragma unroll
    for (int m = 0; m < 2; ++m) {
        const int row = wr * 32 + m * 16 + fr;
        offA[m] = row * 32 + ((fq ^ ((row >> 1) & 3)) << 3);
    }
#pragma unroll
    for (int n = 0; n < WN; ++n) {
        const int row = wc * (WN * 16) + n * 16 + fr;
        offB[n] = row * 32 + ((fq ^ ((row >> 1) & 3)) << 3);
    }

    auto STAGE = [&](int buf, int ko) {
        gld16(gA + ko, dstA0 + buf * 2048 + aofs);
        if constexpr (BN == 128) {
            gld16(gBh + ko, &Bsh[buf][bofs]);
            gld16(gBl + ko, &Bsl[buf][bofs]);
        } else {
            gld16(gB + ko, dstB0 + buf * 2048 + bofs);
        }
    };

    f32x4 acc[2][WN] = {};

    // prologue: stage tile 0 into buffer 0
    STAGE(0, 0);

    const int nk = K >> 5;
    int cur = 0;
    for (int ki = 0; ki < nk; ++ki) {
        const int nxt = (cur == 2) ? 0 : cur + 1;
        if (ki + 1 < nk) {
            STAGE(nxt, (ki + 1) << 5);
            // wait for tile ki only; keep tile ki+1's loads in flight
            asm volatile("s_waitcnt vmcnt(%0)" :: "i"(NV) : "memory");
        } else {
            asm volatile("s_waitcnt vmcnt(0)" ::: "memory");
        }
        __builtin_amdgcn_s_barrier();
        asm volatile("" ::: "memory");   // keep ds_reads below the barrier

        f16x8 ah[2], al[2], bh[WN], bl[WN];
#pragma unroll
        for (int m = 0; m < 2; ++m) {
            ah[m] = *(const f16x8*)(&Ash[cur][offA[m]]);
            al[m] = *(const f16x8*)(&Asl[cur][offA[m]]);
        }
#pragma unroll
        for (int n = 0; n < WN; ++n) {
            bh[n] = *(const f16x8*)(&Bsh[cur][offB[n]]);
            bl[n] = *(const f16x8*)(&Bsl[cur][offB[n]]);
        }
#pragma unroll
        for (int m = 0; m < 2; ++m)
#pragma unroll
            for (int n = 0; n < WN; ++n)
                acc[m][n] = __builtin_amdgcn_mfma_f32_16x16x32_f16(
                    ah[m], bh[n], acc[m][n], 0, 0, 0);
#pragma unroll
        for (int m = 0; m < 2; ++m)
#pragma unroll
            for (int n = 0; n < WN; ++n)
                acc[m][n] = __builtin_amdgcn_mfma_f32_16x16x32_f16(
                    ah[m], bl[n], acc[m][n], 0, 0, 0);
#pragma unroll
        for (int m = 0; m < 2; ++m)
#pragma unroll
            for (int n = 0; n < WN; ++n)
                acc[m][n] = __builtin_amdgcn_mfma_f32_16x16x32_f16(
                    al[m], bh[n], acc[m][n], 0, 0, 0);
        cur = nxt;
    }

    // C/D layout: col = lane&15, row = (lane>>4)*4 + reg   [m89/m91 verified]
#pragma unroll
    for (int m = 0; m < 2; ++m) {
#pragma unroll
        for (int n = 0; n < WN; ++n) {
#pragma unroll
            for (int r = 0; r < 4; ++r) {
                const int row = m0 + wr * 32 + m * 16 + fq * 4 + r;
                const int col = n0 + wc * (WN * 16) + n * 16 + fr;
                float v = acc[m][n][r];
                if (Cadd) v += Cadd[(size_t)row * ldc + col];
                if (radd) v += radd[col];
                if (Cf) Cf[(size_t)row * ldc + col] = v;
                if (Chi) {
                    const f16 hi = (f16)v;
                    Chi[(size_t)row * ldc + col] = hi;
                    Clo[(size_t)row * ldc + col] = (f16)(v - (float)hi);
                }
            }
        }
    }
}

// strided fp32 [rows,cols] (ld) -> contiguous fp16 (hi, lo) pair
__global__ __launch_bounds__(256) void split2d(
    const float* __restrict__ src, int ld, int cols,
    f16* __restrict__ hi, f16* __restrict__ lo, int total4)
{
    const int i = blockIdx.x * 256 + threadIdx.x;
    if (i >= total4) return;
    const int idx = i * 4;
    const int r = idx / cols, c = idx % cols;
    const float4 v = *(const float4*)(src + (size_t)r * ld + c);
    f16x4 h, l;
    h[0] = (f16)v.x; l[0] = (f16)(v.x - (float)h[0]);
    h[1] = (f16)v.y; l[1] = (f16)(v.y - (float)h[1]);
    h[2] = (f16)v.z; l[2] = (f16)(v.z - (float)h[2]);
    h[3] = (f16)v.w; l[3] = (f16)(v.w - (float)h[3]);
    *(f16x4*)(hi + idx) = h;
    *(f16x4*)(lo + idx) = l;
}

// rsum[j] = sum_{k<K} W[j,k]   (the (x+1)-vs-x correction for t==0), fp32
__global__ __launch_bounds__(256) void rowsum_kernel(
    const float* __restrict__ W, int ld, int K, float* __restrict__ out)
{
    const int j = blockIdx.x;
    const int tid = threadIdx.x;
    float s = 0.f;
    for (int k = tid; k < K; k += 256) s += W[(size_t)j * ld + k];
#pragma unroll
    for (int off = 32; off; off >>= 1) s += __shfl_down(s, off);
    __shared__ float red[4];
    if ((tid & 63) == 0) red[tid >> 6] = s;
    __syncthreads();
    if (tid == 0) out[j] = red[0] + red[1] + red[2] + red[3];
}

// Per-step ACT halting + weighted accumulation of hidden. 1 block / row.
// s reconstructed as hi+lo (error ~2^-22 rel) so halting decisions match fp32.
// At t==TMAX-1 also emits the fp16 (hi,lo) split of the final hidden row
// (replaces a separate split2d). s_hi/s_lo may alias hidh/hidl — plain
// pointers, thread-local read-then-write at identical offsets.
__global__ __launch_bounds__(256) void halt_accum(
    const f16* s_hi, const f16* s_lo,  // [B,H]
    const float* __restrict__ w_halt,  // [H]
    const float* __restrict__ b_halt,  // [1]
    float* hidden,                     // [B,H] accumulator (in d_out)
    float* __restrict__ ponder,        // [B]   (in d_out)
    float* __restrict__ cumB,          // [B] state
    float* __restrict__ Rv,            // [B] state
    float* __restrict__ nstep,         // [B] state
    int*   __restrict__ halted,        // [B] state
    f16* hidh, f16* hidl,              // written at t==TMAX-1
    int t)
{
    const int b = blockIdx.x;
    const int tid = threadIdx.x;
    const f16x8 vh = *(const f16x8*)(s_hi + (size_t)b * H_SZ + tid * 8);
    const f16x8 vl = *(const f16x8*)(s_lo + (size_t)b * H_SZ + tid * 8);
    float s[8];
#pragma unroll
    for (int j = 0; j < 8; ++j) s[j] = (float)vh[j] + (float)vl[j];
    const float4 w0 = *(const float4*)(w_halt + tid * 8);
    const float4 w1 = *(const float4*)(w_halt + tid * 8 + 4);
    float part = s[0] * w0.x + s[1] * w0.y + s[2] * w0.z + s[3] * w0.w
               + s[4] * w1.x + s[5] * w1.y + s[6] * w1.z + s[7] * w1.w;
#pragma unroll
    for (int off = 32; off; off >>= 1) part += __shfl_down(part, off);

    __shared__ float red[4];
    __shared__ float w_sh;
    if ((tid & 63) == 0) red[tid >> 6] = part;
    __syncthreads();
    if (tid == 0) {
        const float dot = red[0] + red[1] + red[2] + red[3] + b_halt[0];
        const float p = 1.f / (1.f + expf(-dot));
        const float cb = (t == 0) ? 0.f : cumB[b];
        const int   hd = (t == 0) ? 0   : halted[b];
        float w;
        if (hd) {
            w = 0.f;
        } else if (cb + p >= 0.99f || t == TMAX - 1) {
            w = 1.f - cb;                 // remainder R
            halted[b] = 1;
            Rv[b] = w;
            nstep[b] = (float)t;
        } else {
            w = p;
            cumB[b] = cb + p;
            if (t == 0) halted[b] = 0;
        }
        w_sh = w;
        if (t == TMAX - 1) ponder[b] = nstep[b] + 1.f + Rv[b];
    }
    __syncthreads();
    const float w = w_sh;
    const bool skip = (t > 0 && w == 0.f);   // halted rows contribute nothing

    float* hrow = hidden + (size_t)b * H_SZ + tid * 8;
    float hv[8];
    if (!skip) {
        if (t == 0) {
#pragma unroll
            for (int j = 0; j < 8; ++j) hv[j] = w * s[j];
        } else {
            const float4 h0 = *(const float4*)(hrow);
            const float4 h1 = *(const float4*)(hrow + 4);
            hv[0] = h0.x + w * s[0]; hv[1] = h0.y + w * s[1];
            hv[2] = h0.z + w * s[2]; hv[3] = h0.w + w * s[3];
            hv[4] = h1.x + w * s[4]; hv[5] = h1.y + w * s[5];
            hv[6] = h1.z + w * s[6]; hv[7] = h1.w + w * s[7];
        }
        *(float4*)(hrow)     = make_float4(hv[0], hv[1], hv[2], hv[3]);
        *(float4*)(hrow + 4) = make_float4(hv[4], hv[5], hv[6], hv[7]);
    }
    if (t == TMAX - 1) {
        if (skip) {
            const float4 h0 = *(const float4*)(hrow);
            const float4 h1 = *(const float4*)(hrow + 4);
            hv[0] = h0.x; hv[1] = h0.y; hv[2] = h0.z; hv[3] = h0.w;
            hv[4] = h1.x; hv[5] = h1.y; hv[6] = h1.z; hv[7] = h1.w;
        }
        f16x8 hh, hl;
#pragma unroll
        for (int j = 0; j < 8; ++j) {
            const f16 hi = (f16)hv[j];
            hh[j] = hi;
            hl[j] = (f16)(hv[j] - (float)hi);
        }
        *(f16x8*)(hidh + (size_t)b * H_SZ + tid * 8) = hh;
        *(f16x8*)(hidl + (size_t)b * H_SZ + tid * 8) = hl;
    }
}

extern "C" void kernel_launch(void* const* d_in, const int* in_sizes, int n_in,
                              void* d_out, int out_size, void* d_ws, size_t ws_size,
                              hipStream_t stream)
{
    const float* x        = (const float*)d_in[0];   // [B, D_IN]
    const float* h        = (const float*)d_in[1];   // [B, H]
    const float* W_hidden = (const float*)d_in[2];   // [H, D_IN+H]
    const float* b_hidden = (const float*)d_in[3];   // [H]
    const float* w_halt   = (const float*)d_in[4];   // [H]
    const float* b_halt   = (const float*)d_in[5];   // [1]
    const float* W_out    = (const float*)d_in[6];   // [D_OUT, H]
    const float* b_out    = (const float*)d_in[7];   // [D_OUT]

    float* out    = (float*)d_out;
    float* output = out;                                   // [B, D_OUT]
    float* hidden = out + (size_t)B_SZ * D_OUTN;           // [B, H]
    float* ponder = hidden + (size_t)B_SZ * H_SZ;          // [B]

    // ---- workspace layout ----
    float* ws     = (float*)d_ws;
    float* xc     = ws;                                    // [B,H] fp32 16MB
    float* rsum   = xc + (size_t)B_SZ * H_SZ;              // [H]
    float* cumB   = rsum + H_SZ;                           // [B]
    float* Rv     = cumB + B_SZ;                           // [B]
    float* nstep  = Rv + B_SZ;                             // [B]
    int*   halted = (int*)(nstep + B_SZ);                  // [B]
    f16*   fh     = (f16*)(halted + B_SZ);
    f16* xh  = fh;                         // [B,D_IN]  4MB
    f16* xl  = xh  + (size_t)B_SZ * D_INN;
    f16* sh0 = xl  + (size_t)B_SZ * D_INN; // [B,H] 8MB
    f16* sl0 = sh0 + (size_t)B_SZ * H_SZ;
    f16* sh1 = sl0 + (size_t)B_SZ * H_SZ;
    f16* sl1 = sh1 + (size_t)B_SZ * H_SZ;
    f16* Wxh = sl1 + (size_t)B_SZ * H_SZ;  // [H,D_IN] 4MB
    f16* Wxl = Wxh + (size_t)H_SZ * D_INN;
    f16* Wsh = Wxl + (size_t)H_SZ * D_INN; // [H,H] 8MB
    f16* Wsl = Wsh + (size_t)H_SZ * H_SZ;
    f16* Woh = Wsl + (size_t)H_SZ * H_SZ;  // [D_OUT,H] 4MB
    f16* Wol = Woh + (size_t)D_OUTN * H_SZ;
    f16* hidh = sh0;                       // reuse after the t-loop (aliases
    f16* hidl = sl0;                       // t=11's s_new; safe: see halt_accum)

    const dim3 blk(256);
    const dim3 gblk(512);
    const int LDW = D_INN + H_SZ;  // 3072

    // one-time fp32 -> fp16 (hi,lo) splits
    split2d<<<dim3(B_SZ * D_INN / 4 / 256), blk, 0, stream>>>(
        x, D_INN, D_INN, xh, xl, B_SZ * D_INN / 4);
    split2d<<<dim3(B_SZ * H_SZ / 4 / 256), blk, 0, stream>>>(
        h, H_SZ, H_SZ, sh0, sl0, B_SZ * H_SZ / 4);
    split2d<<<dim3(H_SZ * D_INN / 4 / 256), blk, 0, stream>>>(
        W_hidden, LDW, D_INN, Wxh, Wxl, H_SZ * D_INN / 4);
    split2d<<<dim3(H_SZ * H_SZ / 4 / 256), blk, 0, stream>>>(
        W_hidden + D_INN, LDW, H_SZ, Wsh, Wsl, H_SZ * H_SZ / 4);
    split2d<<<dim3(D_OUTN * H_SZ / 4 / 256), blk, 0, stream>>>(
        W_out, H_SZ, H_SZ, Woh, Wol, D_OUTN * H_SZ / 4);

    // rsum[j] = sum_k W_x[j,k]   (xin = x+1 correction at t==0)
    rowsum_kernel<<<dim3(H_SZ), blk, 0, stream>>>(W_hidden, LDW, D_INN, rsum);

    // grids (1-D, XCD-swizzled in-kernel; all % 8 == 0)
    const int g_step = (B_SZ / 64) * (H_SZ / 128);    // 32*16 = 512
    const int g_out  = (B_SZ / 64) * (D_OUTN / 64);   // 32*16 = 512

    // xc = x @ W_x^T + b_hidden   (loop-invariant part, fp32)
    gemm_split<128><<<dim3(g_step), gblk, 0, stream>>>(
        xh, xl, D_INN, Wxh, Wxl, D_INN, nullptr, b_hidden,
        xc, nullptr, nullptr, H_SZ, D_INN, H_SZ / 128);

    for (int t = 0; t < TMAX; ++t) {
        const f16* ph = (t & 1) ? sh1 : sh0;
        const f16* pl = (t & 1) ? sl1 : sl0;
        f16*       nh = (t & 1) ? sh0 : sh1;
        f16*       nl = (t & 1) ? sl0 : sl1;
        // s_new = s_prev @ W_s^T + xc (+ rsum at t==0), written as (hi,lo)
        gemm_split<128><<<dim3(g_step), gblk, 0, stream>>>(
            ph, pl, H_SZ, Wsh, Wsl, H_SZ, xc, (t == 0) ? rsum : nullptr,
            nullptr, nh, nl, H_SZ, H_SZ, H_SZ / 128);
        halt_accum<<<dim3(B_SZ), blk, 0, stream>>>(
            nh, nl, w_halt, b_halt, hidden, ponder, cumB, Rv, nstep, halted,
            hidh, hidl, t);
    }

    // output = hidden @ W_out^T + b_out   (Σw = 1 ⇒ projection commutes)
    // BN=64 variant: grid 512 = 2 blocks/CU (BN=128 would give 256 = 1/CU)
    gemm_split<64><<<dim3(g_out), gblk, 0, stream>>>(
        hidh, hidl, H_SZ, Woh, Wol, H_SZ, nullptr, b_out,
        output, nullptr, nullptr, D_OUTN, H_SZ, D_OUTN / 64);
}

// Round 13
// 604.315 us; speedup vs baseline: 1.8325x; 1.6166x over previous
//
#include <hip/hip_runtime.h>
#include <hip/hip_bf16.h>
#include <cstdint>

#define B_SZ   2048
#define D_INN  1024
#define H_SZ   2048
#define D_OUTN 1024
#define TMAX   12
#define LDW    3072

typedef _Float16 f16;
typedef __attribute__((ext_vector_type(8))) _Float16 f16x8;
typedef __attribute__((ext_vector_type(4))) float    f32x4;

typedef const __attribute__((address_space(1))) uint32_t* gptr_t;
typedef __attribute__((address_space(3))) uint32_t*       lptr_t;
__device__ inline void gld16(const void* g, void* l) {   // 16B global->LDS DMA
    __builtin_amdgcn_global_load_lds((gptr_t)g, (lptr_t)l, 16, 0, 0);
}

// ---------------------------------------------------------------------------
// Single-fp16 NT GEMM (halt dots now come from the exact fp64 linear path, so
// the 3-term Markidis split is no longer needed — state only feeds hidden,
// which tolerates fp16 with 16x margin per round-2 evidence).
// r7-verified schedule at BK=64: 64xBN tile, 512 thr / 8 waves (2x4 grid,
// wave tile 32x(BN/4)); 3 LDS buffers; in-loop STAGE(ki+1) -> vmcnt(NV) ->
// s_barrier (counted, never 0 in-loop); XOR swizzle c^=(c>>3)&7 on 16B chunks
// within 64-f16 rows (read: colgrp^(row&7)) -> ~2-way residual (free, m136);
// XCD-chunked bijective blockIdx swizzle. LDS 72KB/48KB -> 2 blocks/CU.
// BK=64 halves the iteration count (32 vs 64) = half the barrier convoys.
// Epilogue: +Cadd +radd; optional Cf (fp32), Cs (fp16); optional FUSED
// hidden accumulation: hid[row][col] (=|+=) wvec[row]*v (weights precomputed
// by the exact halting path), and optional fp16 copy of the final hidden.
// ---------------------------------------------------------------------------
template<int BN>
__global__ __launch_bounds__(512, 4) void gemm16(
    const f16* __restrict__ A, int lda,
    const f16* __restrict__ Bm, int ldb,
    const float* __restrict__ Cadd,   // optional [M,ldc] fp32
    const float* __restrict__ radd,   // optional [N]
    float* __restrict__ Cf,           // optional fp32 out
    f16* __restrict__ Cs,             // optional fp16 out
    float* __restrict__ hid,          // optional fused hidden accumulator
    const float* __restrict__ wvec,   // [M] per-row ACT weight (with hid)
    int hacc,                         // 0: overwrite, 1: accumulate
    f16* __restrict__ hid16,          // optional fp16 copy of hidden
    int ldc, int K, int nx)
{
    constexpr int WN = BN / 64;             // n-frags per wave (2 or 1)
    constexpr int NV = (BN == 128) ? 3 : 2; // vmem loads/thread/STAGE
    __shared__ __align__(16) f16 As[3][64 * 64];
    __shared__ __align__(16) f16 Bs[3][BN * 64];
    const int tid  = threadIdx.x;
    const int wave = tid >> 6;
    const int lane = tid & 63;

    const int nwg = gridDim.x;
    const int cpx = nwg >> 3;
    const int bid = (blockIdx.x & 7) * cpx + (blockIdx.x >> 3);
    const int m0 = (bid / nx) * 64, n0 = (bid % nx) * BN;

    const int wr = wave >> 2, wc = wave & 3;      // 2x4 wave grid
    const int fr = lane & 15, fq = lane >> 4;

    // staging: chunk c (16B) -> LDS slot c (linear); global source chunk
    // swizzled by the involution c ^= ((c>>3)&7)  (row = c>>3, 8 chunks/row)
    const int acs = tid ^ ((tid >> 3) & 7);                    // A: 512 chunks
    const f16* gA = A + (size_t)(m0 + (acs >> 3)) * lda + (acs & 7) * 8;
    const int adst = wave << 9;        // wave-uniform dest base (f16 units)
    const int bcs1 = tid ^ ((tid >> 3) & 7);                   // B chunk tid
    const f16* gB1 = Bm + (size_t)(n0 + (bcs1 >> 3)) * ldb + (bcs1 & 7) * 8;
    const int bdst1 = wave << 9;
    const f16* gB2 = nullptr;
    int bdst2 = 0;
    if constexpr (BN == 128) {                                 // B chunk tid+512
        const int bc2 = tid + 512;
        const int bcs2 = bc2 ^ ((bc2 >> 3) & 7);
        gB2 = Bm + (size_t)(n0 + (bcs2 >> 3)) * ldb + (bcs2 & 7) * 8;
        bdst2 = 4096 + (wave << 9);
    }

    // swizzled fragment read offsets (f16 units), k-invariant
    int offA[2][2], offB[WN][2];
#pragma unroll
    for (int m = 0; m < 2; ++m)
#pragma unroll
        for (int ks = 0; ks < 2; ++ks) {
            const int row = wr * 32 + m * 16 + fr;
            offA[m][ks] = row * 64 + (((ks * 4 + fq) ^ (row & 7)) << 3);
        }
#pragma unroll
    for (int n = 0; n < WN; ++n)
#pragma unroll
        for (int ks = 0; ks < 2; ++ks) {
            const int row = wc * (WN * 16) + n * 16 + fr;
            offB[n][ks] = row * 64 + (((ks * 4 + fq) ^ (row & 7)) << 3);
        }

    auto STAGE = [&](int buf, int ko) {
        gld16(gA + ko,  &As[buf][0] + adst);
        gld16(gB1 + ko, &Bs[buf][0] + bdst1);
        if constexpr (BN == 128) gld16(gB2 + ko, &Bs[buf][0] + bdst2);
    };

    f32x4 acc[2][WN] = {};

    STAGE(0, 0);
    const int nk = K >> 6;
    int cur = 0;
    for (int ki = 0; ki < nk; ++ki) {
        const int nxt = (cur == 2) ? 0 : cur + 1;
        if (ki + 1 < nk) {
            STAGE(nxt, (ki + 1) << 6);
            asm volatile("s_waitcnt vmcnt(%0)" :: "i"(NV) : "memory");
        } else {
            asm volatile("s_waitcnt vmcnt(0)" ::: "memory");
        }
        __builtin_amdgcn_s_barrier();
        asm volatile("" ::: "memory");   // keep ds_reads below the barrier

        f16x8 a[2][2], b[WN][2];
#pragma unroll
        for (int m = 0; m < 2; ++m)
#pragma unroll
            for (int ks = 0; ks < 2; ++ks)
                a[m][ks] = *(const f16x8*)(&As[cur][offA[m][ks]]);
#pragma unroll
        for (int n = 0; n < WN; ++n)
#pragma unroll
            for (int ks = 0; ks < 2; ++ks)
                b[n][ks] = *(const f16x8*)(&Bs[cur][offB[n][ks]]);
#pragma unroll
        for (int ks = 0; ks < 2; ++ks)
#pragma unroll
            for (int m = 0; m < 2; ++m)
#pragma unroll
                for (int n = 0; n < WN; ++n)
                    acc[m][n] = __builtin_amdgcn_mfma_f32_16x16x32_f16(
                        a[m][ks], b[n][ks], acc[m][n], 0, 0, 0);
        cur = nxt;
    }

    // epilogue. C/D layout: col = lane&15, row = (lane>>4)*4 + reg
    float wr8[2][4];
    if (hid) {
#pragma unroll
        for (int m = 0; m < 2; ++m)
#pragma unroll
            for (int r = 0; r < 4; ++r)
                wr8[m][r] = wvec[m0 + wr * 32 + m * 16 + fq * 4 + r];
    }
#pragma unroll
    for (int m = 0; m < 2; ++m) {
#pragma unroll
        for (int n = 0; n < WN; ++n) {
#pragma unroll
            for (int r = 0; r < 4; ++r) {
                const int row = m0 + wr * 32 + m * 16 + fq * 4 + r;
                const int col = n0 + wc * (WN * 16) + n * 16 + fr;
                const size_t o = (size_t)row * ldc + col;
                float v = acc[m][n][r];
                if (Cadd) v += Cadd[o];
                if (radd) v += radd[col];
                if (Cf) Cf[o] = v;
                if (Cs) Cs[o] = (f16)v;
                if (hid) {
                    const float hv = hacc ? hid[o] + wr8[m][r] * v
                                          : wr8[m][r] * v;
                    hid[o] = hv;
                    if (hid16) hid16[o] = (f16)hv;
                }
            }
        }
    }
}

// strided fp32 [rows,cols] (ld) -> contiguous fp16
__global__ __launch_bounds__(256) void cast16(
    const float* __restrict__ src, int ld, int cols,
    f16* __restrict__ dst, int total8)
{
    const int i = blockIdx.x * 256 + threadIdx.x;
    if (i >= total8) return;
    const int idx = i * 8;
    const int r = idx / cols, c = idx % cols;
    const float4 v0 = *(const float4*)(src + (size_t)r * ld + c);
    const float4 v1 = *(const float4*)(src + (size_t)r * ld + c + 4);
    f16x8 o;
    o[0]=(f16)v0.x; o[1]=(f16)v0.y; o[2]=(f16)v0.z; o[3]=(f16)v0.w;
    o[4]=(f16)v1.x; o[5]=(f16)v1.y; o[6]=(f16)v1.z; o[7]=(f16)v1.w;
    *(f16x8*)(dst + idx) = o;
}

// rsum[j] = sum_k W[j,k]  (x+1 correction for the t==0 STATE path), fp32
__global__ __launch_bounds__(256) void rowsum_kernel(
    const float* __restrict__ W, int ld, int K, float* __restrict__ out)
{
    const int j = blockIdx.x;
    const int tid = threadIdx.x;
    float s = 0.f;
    for (int k = tid; k < K; k += 256) s += W[(size_t)j * ld + k];
#pragma unroll
    for (int off = 32; off; off >>= 1) s += __shfl_down(s, off);
    __shared__ float red[4];
    if ((tid & 63) == 0) red[tid >> 6] = s;
    __syncthreads();
    if (tid == 0) out[j] = red[0] + red[1] + red[2] + red[3];
}

// W_hidden [R=2048][C=3072] fp32 -> WT [C][R]  (for coalesced fp64 matvecs)
__global__ __launch_bounds__(256) void transpose_w(
    const float* __restrict__ in, float* __restrict__ out, int R, int C)
{
    __shared__ float t[32][33];
    const int bc = blockIdx.x * 32, br = blockIdx.y * 32;
    const int tx = threadIdx.x & 31, ty = threadIdx.x >> 5;   // 32 x 8
#pragma unroll
    for (int i = 0; i < 32; i += 8)
        t[ty + i][tx] = in[(size_t)(br + ty + i) * C + bc + tx];
    __syncthreads();
#pragma unroll
    for (int i = 0; i < 32; i += 8)
        out[(size_t)(bc + ty + i) * R + br + tx] = t[tx][ty + i];
}

__global__ __launch_bounds__(256) void init_u0(
    const float* __restrict__ w, double* __restrict__ u)
{
    const int i = blockIdx.x * 256 + threadIdx.x;
    if (i < H_SZ) u[i] = (double)w[i];
}

// u_out[i] = sum_j W_s[j,i] u_in[j] = sum_j WT[D_INN+i][j] u_in[j]  (fp64)
__global__ __launch_bounds__(256) void gemv_t(
    const float* __restrict__ WT, const double* __restrict__ uin,
    double* __restrict__ uout)
{
    const int i = blockIdx.x;
    const int tid = threadIdx.x;
    const float* row = WT + (size_t)(D_INN + i) * H_SZ;
    double acc = 0.0;
    for (int j = tid; j < H_SZ; j += 256) acc += (double)row[j] * uin[j];
#pragma unroll
    for (int off = 32; off; off >>= 1) acc += __shfl_down(acc, off);
    __shared__ double red[4];
    if ((tid & 63) == 0) red[tid >> 6] = acc;
    __syncthreads();
    if (tid == 0) uout[i] = red[0] + red[1] + red[2] + red[3];
}

// XU[t][k] = (W_x^T v_t)[k], XS[t][k] = (W_x^T u_t)[k], v_t = sum_{s<=t} u_s
__global__ __launch_bounds__(256) void batch_wx(
    const float* __restrict__ WT, const double* __restrict__ U,
    double* __restrict__ XU, double* __restrict__ XS)
{
    const int k = blockIdx.x;          // 0..D_INN-1
    const int tid = threadIdx.x;
    const float* row = WT + (size_t)k * H_SZ;
    double au[TMAX] = {}, av[TMAX] = {};
    for (int j = tid; j < H_SZ; j += 256) {
        const double w = (double)row[j];
        double pref = 0.0;
#pragma unroll
        for (int t = 0; t < TMAX; ++t) {
            const double u = U[(size_t)t * H_SZ + j];
            pref += u;
            au[t] += w * u;
            av[t] += w * pref;
        }
    }
    __shared__ double red[4][2 * TMAX];
#pragma unroll
    for (int t = 0; t < TMAX; ++t) {
#pragma unroll
        for (int off = 32; off; off >>= 1) {
            au[t] += __shfl_down(au[t], off);
            av[t] += __shfl_down(av[t], off);
        }
    }
    if ((tid & 63) == 0) {
#pragma unroll
        for (int t = 0; t < TMAX; ++t) {
            red[tid >> 6][t] = au[t];
            red[tid >> 6][TMAX + t] = av[t];
        }
    }
    __syncthreads();
    if (tid == 0) {
#pragma unroll
        for (int t = 0; t < TMAX; ++t) {
            XS[(size_t)t * D_INN + k] = red[0][t] + red[1][t] + red[2][t] + red[3][t];
            XU[(size_t)t * D_INN + k] = red[0][TMAX+t] + red[1][TMAX+t]
                                      + red[2][TMAX+t] + red[3][TMAX+t];
        }
    }
}

// E[t] = sum_k XS[t][k] + v_t . b_hidden
__global__ __launch_bounds__(256) void e_kernel(
    const double* __restrict__ XS, const double* __restrict__ U,
    const float* __restrict__ bh, double* __restrict__ E)
{
    const int t = blockIdx.x;
    const int tid = threadIdx.x;
    double a = 0.0;
    for (int k = tid; k < D_INN; k += 256) a += XS[(size_t)t * D_INN + k];
    for (int j = tid; j < H_SZ; j += 256) {
        double v = 0.0;
        for (int s = 0; s <= t; ++s) v += U[(size_t)s * H_SZ + j];
        a += v * (double)bh[j];
    }
#pragma unroll
    for (int off = 32; off; off >>= 1) a += __shfl_down(a, off);
    __shared__ double red[4];
    if ((tid & 63) == 0) red[tid >> 6] = a;
    __syncthreads();
    if (tid == 0) E[t] = red[0] + red[1] + red[2] + red[3];
}

// D[b][t] = u_{t+1}.h[b] + XU[t].x[b] + E[t]   (fp64)
__global__ __launch_bounds__(256) void d_kernel(
    const float* __restrict__ h, const float* __restrict__ x,
    const double* __restrict__ U, const double* __restrict__ XU,
    const double* __restrict__ E, double* __restrict__ Dm)
{
    const int b = blockIdx.x;
    const int tid = threadIdx.x;
    double acc[TMAX] = {};
    for (int i = tid; i < H_SZ; i += 256) {
        const double hv = (double)h[(size_t)b * H_SZ + i];
#pragma unroll
        for (int t = 0; t < TMAX; ++t)
            acc[t] += hv * U[(size_t)(t + 1) * H_SZ + i];
    }
    for (int i = tid; i < D_INN; i += 256) {
        const double xv = (double)x[(size_t)b * D_INN + i];
#pragma unroll
        for (int t = 0; t < TMAX; ++t)
            acc[t] += xv * XU[(size_t)t * D_INN + i];
    }
    __shared__ double red[4][TMAX];
#pragma unroll
    for (int t = 0; t < TMAX; ++t)
#pragma unroll
        for (int off = 32; off; off >>= 1) acc[t] += __shfl_down(acc[t], off);
    if ((tid & 63) == 0)
#pragma unroll
        for (int t = 0; t < TMAX; ++t) red[tid >> 6][t] = acc[t];
    __syncthreads();
    if (tid == 0)
#pragma unroll
        for (int t = 0; t < TMAX; ++t)
            Dm[(size_t)b * TMAX + t] =
                red[0][t] + red[1][t] + red[2][t] + red[3][t] + E[t];
}

// Full ACT halting schedule from the exact dots: w_t[b], ponder[b]
__global__ __launch_bounds__(256) void sched_kernel(
    const double* __restrict__ Dm, const float* __restrict__ b_halt,
    float* __restrict__ Wmat, float* __restrict__ ponder)
{
    const int b = blockIdx.x * 256 + threadIdx.x;
    if (b >= B_SZ) return;
    const float bh = b_halt[0];
    float cum = 0.f, R = 0.f;
    int n = -1;
    float w[TMAX];
#pragma unroll
    for (int t = 0; t < TMAX; ++t) {
        const float p = 1.f / (1.f + expf(-((float)Dm[(size_t)b * TMAX + t] + bh)));
        if (n < 0) {
            const float c = cum + p;
            if (c >= 0.99f || t == TMAX - 1) { n = t; R = 1.f - cum; w[t] = R; }
            else { w[t] = p; cum = c; }
        } else {
            w[t] = 0.f;
        }
    }
    ponder[b] = (float)(n + 1) + R;
#pragma unroll
    for (int t = 0; t < TMAX; ++t) Wmat[(size_t)t * B_SZ + b] = w[t];
}

extern "C" void kernel_launch(void* const* d_in, const int* in_sizes, int n_in,
                              void* d_out, int out_size, void* d_ws, size_t ws_size,
                              hipStream_t stream)
{
    const float* x        = (const float*)d_in[0];   // [B, D_IN]
    const float* h        = (const float*)d_in[1];   // [B, H]
    const float* W_hidden = (const float*)d_in[2];   // [H, D_IN+H]
    const float* b_hidden = (const float*)d_in[3];   // [H]
    const float* w_halt   = (const float*)d_in[4];   // [H]
    const float* b_halt   = (const float*)d_in[5];   // [1]
    const float* W_out    = (const float*)d_in[6];   // [D_OUT, H]
    const float* b_out    = (const float*)d_in[7];   // [D_OUT]

    float* out    = (float*)d_out;
    float* output = out;                                   // [B, D_OUT]
    float* hidden = out + (size_t)B_SZ * D_OUTN;           // [B, H]
    float* ponder = hidden + (size_t)B_SZ * H_SZ;          // [B]

    // ---- workspace layout (doubles first for alignment) ----
    double* U   = (double*)d_ws;                           // [13][H]
    double* XU  = U  + (size_t)(TMAX + 1) * H_SZ;          // [12][D_IN]
    double* XS  = XU + (size_t)TMAX * D_INN;               // [12][D_IN]
    double* E   = XS + (size_t)TMAX * D_INN;               // [16]
    double* Dm  = E + 16;                                  // [B][12]
    float* rsum = (float*)(Dm + (size_t)B_SZ * TMAX);      // [H]
    float* Wmat = rsum + H_SZ;                             // [12][B]
    float* WT   = Wmat + (size_t)TMAX * B_SZ;              // [3072][2048] 24MB
    float* xc   = WT;                                      // ALIAS: xc (16MB)
                                                           // written after all
                                                           // WT consumers ran
    f16* xh   = (f16*)(WT + (size_t)LDW * H_SZ);           // [B][D_IN]  4MB
    f16* Wxh  = xh  + (size_t)B_SZ * D_INN;                // [H][D_IN]  4MB
    f16* sh0  = Wxh + (size_t)H_SZ * D_INN;                // [B][H]     8MB
    f16* sh1  = sh0 + (size_t)B_SZ * H_SZ;                 // [B][H]     8MB
    f16* Wsh  = sh1 + (size_t)B_SZ * H_SZ;                 // [H][H]     8MB
    f16* Woh  = Wsh + (size_t)H_SZ * H_SZ;                 // [D_OUT][H] 4MB
    f16* hid16 = xh;   // ALIAS xh+Wxh (8MB): both dead before t=11 writes it

    const dim3 blk(256);
    const dim3 gblk(512);

    // ---- one-time casts fp32 -> fp16 ----
    cast16<<<dim3(B_SZ * D_INN / 8 / 256), blk, 0, stream>>>(
        x, D_INN, D_INN, xh, B_SZ * D_INN / 8);
    cast16<<<dim3(B_SZ * H_SZ / 8 / 256), blk, 0, stream>>>(
        h, H_SZ, H_SZ, sh0, B_SZ * H_SZ / 8);
    cast16<<<dim3(H_SZ * D_INN / 8 / 256), blk, 0, stream>>>(
        W_hidden, LDW, D_INN, Wxh, H_SZ * D_INN / 8);
    cast16<<<dim3(H_SZ * H_SZ / 8 / 256), blk, 0, stream>>>(
        W_hidden + D_INN, LDW, H_SZ, Wsh, H_SZ * H_SZ / 8);
    cast16<<<dim3(D_OUTN * H_SZ / 8 / 256), blk, 0, stream>>>(
        W_out, H_SZ, H_SZ, Woh, D_OUTN * H_SZ / 8);

    rowsum_kernel<<<dim3(H_SZ), blk, 0, stream>>>(W_hidden, LDW, D_INN, rsum);

    // ---- exact fp64 halting path ----
    transpose_w<<<dim3(LDW / 32, H_SZ / 32), blk, 0, stream>>>(
        W_hidden, WT, H_SZ, LDW);
    init_u0<<<dim3(H_SZ / 256), blk, 0, stream>>>(w_halt, U);
    for (int k = 0; k < TMAX; ++k)
        gemv_t<<<dim3(H_SZ), blk, 0, stream>>>(WT, U + (size_t)k * H_SZ,
                                               U + (size_t)(k + 1) * H_SZ);
    batch_wx<<<dim3(D_INN), blk, 0, stream>>>(WT, U, XU, XS);
    e_kernel<<<dim3(TMAX), blk, 0, stream>>>(XS, U, b_hidden, E);
    d_kernel<<<dim3(B_SZ), blk, 0, stream>>>(h, x, U, XU, E, Dm);
    sched_kernel<<<dim3(B_SZ / 256), blk, 0, stream>>>(Dm, b_halt, Wmat, ponder);

    // ---- state path (single fp16) ----
    // xc = x @ W_x^T + b_hidden   (overwrites WT region — consumers done)
    gemm16<128><<<dim3((B_SZ / 64) * (H_SZ / 128)), gblk, 0, stream>>>(
        xh, D_INN, Wxh, D_INN, nullptr, b_hidden, xc, nullptr,
        nullptr, nullptr, 0, nullptr, H_SZ, D_INN, H_SZ / 128);

    for (int t = 0; t < TMAX; ++t) {
        const f16* ph = (t & 1) ? sh1 : sh0;
        f16*       nh = (t & 1) ? sh0 : sh1;
        // s_new = s_prev @ W_s^T + xc (+ rsum at t==0); fused
        // hidden (=|+=) w_t[row] * s_new; t==11 also emits fp16 hidden
        gemm16<128><<<dim3((B_SZ / 64) * (H_SZ / 128)), gblk, 0, stream>>>(
            ph, H_SZ, Wsh, H_SZ, xc, (t == 0) ? rsum : nullptr,
            nullptr, nh, hidden, Wmat + (size_t)t * B_SZ, (t > 0),
            (t == TMAX - 1) ? hid16 : nullptr, H_SZ, H_SZ, H_SZ / 128);
    }

    // output = hidden @ W_out^T + b_out   (sum w = 1 => projection commutes)
    gemm16<64><<<dim3((B_SZ / 64) * (D_OUTN / 64)), gblk, 0, stream>>>(
        hid16, H_SZ, Woh, H_SZ, nullptr, b_out, output, nullptr,
        nullptr, nullptr, 0, nullptr, D_OUTN, H_SZ, D_OUTN / 64);
}